// Round 2
// baseline (6837.254 us; speedup 1.0000x reference)
//
#include <hip/hip_runtime.h>
#include <hip/hip_bf16.h>

// Sizes fixed by the problem
#define B_   2048
#define V_   1024
#define H_   512
#define E_   256
#define L_   32

typedef __attribute__((ext_vector_type(8))) short bf16x8;
typedef __attribute__((ext_vector_type(4))) float f32x4;
typedef unsigned short u16;
typedef unsigned int   u32;

__device__ __forceinline__ u16 f2bf(float x) {
    union { float f; u32 u; } v; v.f = x;
    u32 r = v.u + 0x7fffu + ((v.u >> 16) & 1u);   // RNE
    return (u16)(r >> 16);
}
__device__ __forceinline__ float sig_(float x)  { return 1.f / (1.f + __expf(-x)); }
__device__ __forceinline__ float tanh_(float x) { return 1.f - 2.f / (__expf(2.f * x) + 1.f); }

// -------------------------------------------------------------------------
// Preprocess: repack weights (fp32) into bf16 MFMA-fragment-major layouts.
//   value(frag, lane l, elem e) = W[k][n], k = kstep*32 + (l>>4)*8 + e,
//                                          n = nfrag*16 + (l&15)
// w1f : [24 kstep][128 nfrag][64][8]  (K=768 = [e|h], N=2048 gates, n=g*512+j)
// wof : [16 kstep][ 64 vfrag][64][8]  (K=512 hidden, N=1024 vocab)
// wef : [32 kstep][ 16 efrag][64][8]  (K=1024 vocab, N=256 embed)
// b1  : b_ih + b_hh
// -------------------------------------------------------------------------
__global__ void prep(const float* __restrict__ W_ih, const float* __restrict__ W_hh,
                     const float* __restrict__ b_ih, const float* __restrict__ b_hh,
                     const float* __restrict__ W_out, const float* __restrict__ W_emb,
                     u16* __restrict__ w1f, u16* __restrict__ wof, u16* __restrict__ wef,
                     float* __restrict__ b1)
{
    int idx = blockIdx.x * 256 + threadIdx.x;
    if (idx < 1572864) {                       // W1 = [W_ih | W_hh], gates
        int e = idx & 7, lt = (idx >> 3) & 63, nf = (idx >> 9) & 127, ks = idx >> 16;
        int k = ks * 32 + ((lt >> 4) << 3) + e;
        int n = (nf << 4) + (lt & 15);         // n = g*512 + j (natural)
        float v = (k < E_) ? W_ih[n * E_ + k] : W_hh[n * H_ + (k - E_)];
        w1f[idx] = f2bf(v);
    } else if (idx < 2097152) {                // W_out
        int j = idx - 1572864;
        int e = j & 7, lt = (j >> 3) & 63, vf = (j >> 9) & 63, ks = j >> 15;
        int k = ks * 32 + ((lt >> 4) << 3) + e;
        int v = (vf << 4) + (lt & 15);
        wof[j] = f2bf(W_out[v * H_ + k]);
    } else if (idx < 2359296) {                // W_emb
        int j = idx - 2097152;
        int e = j & 7, lt = (j >> 3) & 63, ef = (j >> 9) & 15, ks = j >> 13;
        int k = ks * 32 + ((lt >> 4) << 3) + e;
        int c = (ef << 4) + (lt & 15);
        wef[j] = f2bf(W_emb[c * V_ + k]);
    } else if (idx < 2361344) {                // fused bias
        int j = idx - 2359296;
        b1[j] = b_ih[j] + b_hh[j];
    }
}

// -------------------------------------------------------------------------
// Persistent fused kernel. 128 blocks x 1024 threads (16 waves). Block owns
// 16 batch rows end-to-end over all 32 steps; no inter-block communication.
// N is split 16-way across waves so per-iteration register state is small
// (8 B-frags = 32 VGPR in flight) and loads batch-issue.
//  phase A: gates[16,2048] = ae[16,768] @ W1^T ; LSTM pointwise; h -> LDS
//  phase B: logits[16,1024] = h @ W_out^T ; E=exp(logit+g) ; rowsum; out
//  phase C: e[16,256] = E @ W_emb^T * invsum + b_emb -> LDS
// -------------------------------------------------------------------------
__global__ __launch_bounds__(1024, 4)
void lstm_fused(const float* __restrict__ x, const float* __restrict__ gum,
                const u16* __restrict__ w1f, const u16* __restrict__ wof,
                const u16* __restrict__ wef, const float* __restrict__ b1,
                const float* __restrict__ b_out, const float* __restrict__ b_emb,
                const float* __restrict__ sos, float* __restrict__ out)
{
    __shared__ u16  ae[16][784];    // [b][0:256 e | 256:768 h]; stride%128B==32B
    __shared__ u16  xs[16][1040];   // unnormalized exp(logits) bf16; same trick
    __shared__ float red[16][16];   // per-wave row sums

    const int tid = threadIdx.x;
    const int w   = tid >> 6;       // wave 0..15
    const int l   = tid & 63;
    const int q   = l >> 4;         // quarter-wave
    const int col = l & 15;
    const int r0  = blockIdx.x << 4;

    // EOS row: out[b][32][v] = (v==0)
    for (int i = tid; i < 16 * V_; i += 1024) {
        int b = i >> 10, v = i & (V_ - 1);
        out[((size_t)(r0 + b) * 33 + 32) * V_ + v] = (v == 0) ? 1.f : 0.f;
    }
    // e0 = sos, h0 = x
    for (int i = tid; i < 16 * E_; i += 1024) {
        int b = i >> 8, k = i & (E_ - 1);
        ae[b][k] = f2bf(sos[k]);
    }
    for (int i = tid; i < 16 * H_; i += 1024) {
        int b = i >> 9, k = i & (H_ - 1);
        ae[b][E_ + k] = f2bf(x[(r0 + b) * H_ + k]);
    }

    // hoisted per-thread biases (j = 32w + 16jj + col covers all 512 hidden)
    float bia[2], bfa[2], bga[2], boa[2];
    #pragma unroll
    for (int jj = 0; jj < 2; ++jj) {
        int j = (w << 5) + (jj << 4) + col;
        bia[jj] = b1[j];           bfa[jj] = b1[H_ + j];
        bga[jj] = b1[2 * H_ + j];  boa[jj] = b1[3 * H_ + j];
    }
    float bov[4];
    #pragma unroll
    for (int f = 0; f < 4; ++f) bov[f] = b_out[(w << 6) + (f << 4) + col];
    const float bem = b_emb[(w << 4) + col];

    // per-thread weight base pointers (lane-fixed part of fragment address)
    const u16* w1p = w1f + ((w << 1) << 9) + (l << 3);   // + ks*65536 + g*16384 + jj*512
    const u16* wop = wof + ((w << 2) << 9) + (l << 3);   // + ks*32768 + f*512
    const u16* wep = wef + (w << 9) + (l << 3);          // + ks*8192

    float creg[2][4];               // c state: [jj][r], j=32w+16jj+col, b=4q+r
    #pragma unroll
    for (int jj = 0; jj < 2; ++jj)
        #pragma unroll
        for (int r = 0; r < 4; ++r) creg[jj][r] = 0.f;

    __syncthreads();

    const f32x4 fz = {0.f, 0.f, 0.f, 0.f};

    for (int t = 0; t < L_; ++t) {
        // ---------------- phase A: gates ----------------
        f32x4 acc[4][2];
        #pragma unroll
        for (int g = 0; g < 4; ++g) { acc[g][0] = fz; acc[g][1] = fz; }

        for (int ks = 0; ks < 24; ++ks) {
            bf16x8 af = *(const bf16x8*)&ae[col][ks * 32 + (q << 3)];
            const u16* p = w1p + ks * 65536;
            bf16x8 bb[8];
            #pragma unroll
            for (int g = 0; g < 4; ++g) {
                bb[2 * g]     = *(const bf16x8*)(p + g * 16384);
                bb[2 * g + 1] = *(const bf16x8*)(p + g * 16384 + 512);
            }
            #pragma unroll
            for (int g = 0; g < 4; ++g) {
                acc[g][0] = __builtin_amdgcn_mfma_f32_16x16x32_bf16(af, bb[2 * g],     acc[g][0], 0, 0, 0);
                acc[g][1] = __builtin_amdgcn_mfma_f32_16x16x32_bf16(af, bb[2 * g + 1], acc[g][1], 0, 0, 0);
            }
        }
        __syncthreads();            // everyone done reading ae before h writes
        #pragma unroll
        for (int jj = 0; jj < 2; ++jj) {
            int j = (w << 5) + (jj << 4) + col;
            #pragma unroll
            for (int r = 0; r < 4; ++r) {
                float gi = sig_(acc[0][jj][r] + bia[jj]);
                float gf = sig_(acc[1][jj][r] + bfa[jj]);
                float gg = tanh_(acc[2][jj][r] + bga[jj]);
                float go = sig_(acc[3][jj][r] + boa[jj]);
                float c  = gf * creg[jj][r] + gi * gg;
                creg[jj][r] = c;
                ae[(q << 2) + r][E_ + j] = f2bf(go * tanh_(c));
            }
        }
        __syncthreads();            // h complete before phase B reads it

        // ---------------- phase B: logits + softmax ----------------
        const float* gt = gum + (size_t)t * (B_ * V_) + (size_t)r0 * V_;
        float gr[4][4];             // prefetch gumbel (hidden under MFMA loop)
        #pragma unroll
        for (int f = 0; f < 4; ++f)
            #pragma unroll
            for (int r = 0; r < 4; ++r)
                gr[f][r] = gt[((q << 2) + r) * V_ + (w << 6) + (f << 4) + col];

        f32x4 accB[4];
        #pragma unroll
        for (int f = 0; f < 4; ++f) accB[f] = fz;

        for (int ko = 0; ko < 8; ++ko) {
            int ks = ko << 1;
            bf16x8 a0 = *(const bf16x8*)&ae[col][E_ + ks * 32 + (q << 3)];
            bf16x8 a1 = *(const bf16x8*)&ae[col][E_ + ks * 32 + 32 + (q << 3)];
            const u16* p = wop + ks * 32768;
            bf16x8 bb[8];
            #pragma unroll
            for (int f = 0; f < 4; ++f) {
                bb[f]     = *(const bf16x8*)(p + f * 512);
                bb[4 + f] = *(const bf16x8*)(p + 32768 + f * 512);
            }
            #pragma unroll
            for (int f = 0; f < 4; ++f)
                accB[f] = __builtin_amdgcn_mfma_f32_16x16x32_bf16(a0, bb[f], accB[f], 0, 0, 0);
            #pragma unroll
            for (int f = 0; f < 4; ++f)
                accB[f] = __builtin_amdgcn_mfma_f32_16x16x32_bf16(a1, bb[4 + f], accB[f], 0, 0, 0);
        }

        float eb[4][4];
        float ps[4] = {0.f, 0.f, 0.f, 0.f};
        #pragma unroll
        for (int f = 0; f < 4; ++f) {
            #pragma unroll
            for (int r = 0; r < 4; ++r) {
                // no max-subtraction: logits+gumbel <= ~20 -> exp safe in fp32
                float Ee = __expf(accB[f][r] + bov[f] + gr[f][r]);
                eb[f][r] = Ee;
                ps[r] += Ee;
            }
        }
        #pragma unroll
        for (int m = 1; m < 16; m <<= 1)
            #pragma unroll
            for (int r = 0; r < 4; ++r) ps[r] += __shfl_xor(ps[r], m, 64);
        if (col == 0) {
            #pragma unroll
            for (int r = 0; r < 4; ++r) red[(q << 2) + r][w] = ps[r];
        }
        #pragma unroll
        for (int f = 0; f < 4; ++f) {          // stage unnormalized exp as bf16
            int v = (w << 6) + (f << 4) + col;
            #pragma unroll
            for (int r = 0; r < 4; ++r) xs[(q << 2) + r][v] = f2bf(eb[f][r]);
        }
        __syncthreads();            // red + xs visible to all
        float invs[4];
        #pragma unroll
        for (int r = 0; r < 4; ++r) {
            float s = 0.f;
            #pragma unroll
            for (int ww = 0; ww < 16; ++ww) s += red[(q << 2) + r][ww];
            invs[r] = 1.f / s;
        }
        #pragma unroll
        for (int f = 0; f < 4; ++f) {          // write normalized softmax (fp32)
            int v = (w << 6) + (f << 4) + col;
            #pragma unroll
            for (int r = 0; r < 4; ++r) {
                int b = (q << 2) + r;
                out[((size_t)(r0 + b) * 33 + t) * V_ + v] = eb[f][r] * invs[r];
            }
        }

        // ---------------- phase C: e_new ----------------
        f32x4 accC = fz;
        for (int ko = 0; ko < 4; ++ko) {
            const u16* p = wep + (ko << 3) * 8192;
            bf16x8 bb[8];
            #pragma unroll
            for (int s = 0; s < 8; ++s) bb[s] = *(const bf16x8*)(p + s * 8192);
            #pragma unroll
            for (int s = 0; s < 8; ++s) {
                bf16x8 af = *(const bf16x8*)&xs[col][((ko << 3) + s) * 32 + (q << 3)];
                accC = __builtin_amdgcn_mfma_f32_16x16x32_bf16(af, bb[s], accC, 0, 0, 0);
            }
        }
        // e_new = (E @ W_emb^T) * invsum + b_emb   (linearity of the GEMM)
        {
            int ce = (w << 4) + col;
            #pragma unroll
            for (int r = 0; r < 4; ++r)
                ae[(q << 2) + r][ce] = f2bf(accC[r] * invs[r] + bem);
        }
        __syncthreads();            // e complete before next step's phase A
    }
}

extern "C" void kernel_launch(void* const* d_in, const int* in_sizes, int n_in,
                              void* d_out, int out_size, void* d_ws, size_t ws_size,
                              hipStream_t stream) {
    const float* x     = (const float*)d_in[0];
    const float* gum   = (const float*)d_in[1];
    const float* W_ih  = (const float*)d_in[2];
    const float* W_hh  = (const float*)d_in[3];
    const float* b_ih  = (const float*)d_in[4];
    const float* b_hh  = (const float*)d_in[5];
    const float* W_out = (const float*)d_in[6];
    const float* b_out = (const float*)d_in[7];
    const float* W_emb = (const float*)d_in[8];
    const float* b_emb = (const float*)d_in[9];
    const float* sos   = (const float*)d_in[10];
    float* out = (float*)d_out;

    // workspace layout (needs ~4.73 MB): bf16 fragment weights + fused bias
    char* ws = (char*)d_ws;
    u16*  w1f = (u16*)(ws);                    // 3,145,728 B
    u16*  wof = (u16*)(ws + 3145728);          // 1,048,576 B
    u16*  wef = (u16*)(ws + 4194304);          //   524,288 B
    float* b1 = (float*)(ws + 4718592);        //     8,192 B

    prep<<<9224, 256, 0, stream>>>(W_ih, W_hh, b_ih, b_hh, W_out, W_emb,
                                   w1f, wof, wef, b1);
    lstm_fused<<<128, 1024, 0, stream>>>(x, gum, w1f, wof, wef, b1,
                                         b_out, b_emb, sos, out);
}

// Round 3
// 1904.541 us; speedup vs baseline: 3.5900x; 3.5900x over previous
//
#include <hip/hip_runtime.h>
#include <hip/hip_bf16.h>

#define B_   2048
#define V_   1024
#define H_   512
#define E_   256
#define L_   32

typedef __attribute__((ext_vector_type(8))) short bf16x8;
typedef __attribute__((ext_vector_type(4))) float f32x4;
typedef unsigned short u16;
typedef unsigned int   u32;
typedef unsigned char  u8;
typedef long long      i64;

__device__ __forceinline__ u16 f2bf(float x) {
    union { float f; u32 u; } v; v.f = x;
    u32 r = v.u + 0x7fffu + ((v.u >> 16) & 1u);   // RNE
    return (u16)(r >> 16);
}
// OCP e4m3fn encode, RNE, flush below 2^-6 (callers pre-scale so this is negligible)
__device__ __forceinline__ u8 f2e4m3(float x) {
    union { float f; u32 u; } v; v.f = x;
    u32 s = (v.u >> 24) & 0x80u;
    u32 a = v.u & 0x7fffffffu;
    if (a < 0x3c800000u) return (u8)s;            // |x| < 2^-6 -> 0
    if (a > 0x43e00000u) a = 0x43e00000u;         // clamp 448
    u32 r = a + 0x000fffffu + ((a >> 20) & 1u);   // RNE to 3-bit mantissa
    if (r > 0x43e00000u) r = 0x43e00000u;
    u32 ex = (r >> 23) - 120u;                    // biased e4m3 exponent (bias 7)
    u32 mn = (r >> 20) & 7u;
    return (u8)(s | (ex << 3) | mn);
}
__device__ __forceinline__ float sig_(float x)  { return 1.f / (1.f + __expf(-x)); }
__device__ __forceinline__ float tanh_(float x) { return 1.f - 2.f / (__expf(2.f * x) + 1.f); }

// -------------------------------------------------------------------------
// Weight layouts (fragment-linear, DMA-stream order):
// w1f (fp8, x64): [ks 24][g 4][m 32][l 64][e 8]   k=ks*32+(l>>4)*8+e,
//                 n = g*512 + (m>>1)*32 + (m&1)*16 + (l&15)   (m = 2w+jj)
// wof (bf16)    : [half 2][ks 16][m 32][l 64][e 8] v = half*512+(m>>1)*32+(m&1)*16+(l&15)
// wef (fp8, x64): [c 16][m 16][s 2][l 64][e 8]     k=(2c+s)*32+(l>>4)*8+e, col=m*16+(l&15)
// b1 = b_ih + b_hh (fp32)
// -------------------------------------------------------------------------
__global__ void prep(const float* __restrict__ W_ih, const float* __restrict__ W_hh,
                     const float* __restrict__ b_ih, const float* __restrict__ b_hh,
                     const float* __restrict__ W_out, const float* __restrict__ W_emb,
                     u8* __restrict__ w1f, u16* __restrict__ wof, u8* __restrict__ wef,
                     float* __restrict__ b1)
{
    int idx = blockIdx.x * 256 + threadIdx.x;
    if (idx < 1572864) {                       // W1 = [W_ih | W_hh] -> fp8*64
        int e = idx & 7, l = (idx >> 3) & 63, m = (idx >> 9) & 31, g = (idx >> 14) & 3, ks = idx >> 16;
        int k = ks * 32 + ((l >> 4) << 3) + e;
        int n = g * 512 + ((m >> 1) << 5) + ((m & 1) << 4) + (l & 15);
        float v = (k < E_) ? W_ih[n * E_ + k] : W_hh[n * H_ + (k - E_)];
        w1f[idx] = f2e4m3(v * 64.f);
    } else if (idx < 2097152) {                // W_out -> bf16
        int j = idx - 1572864;
        int e = j & 7, l = (j >> 3) & 63, m = (j >> 9) & 31, ks = (j >> 14) & 15, hf = (j >> 18);
        int k = ks * 32 + ((l >> 4) << 3) + e;
        int v = hf * 512 + ((m >> 1) << 5) + ((m & 1) << 4) + (l & 15);
        wof[j] = f2bf(W_out[v * H_ + k]);
    } else if (idx < 2359296) {                // W_emb -> fp8*64
        int j = idx - 2097152;
        int e = j & 7, l = (j >> 3) & 63, s = (j >> 9) & 1, m = (j >> 10) & 15, c = j >> 14;
        int k = (2 * c + s) * 32 + ((l >> 4) << 3) + e;
        int ce = m * 16 + (l & 15);
        wef[j] = f2e4m3(W_emb[ce * V_ + k] * 64.f);
    } else if (idx < 2361344) {
        int j = idx - 2359296;
        b1[j] = b_ih[j] + b_hh[j];
    }
}

// LDS layout (bytes)
#define STG   0u        // staging: A/C 4 slots x 16384, B 3 slots x 32768 (96 KiB)
#define AEO   98304u    // 16 x 776 fp8: [0,256) e*16, [256,768) h*16
#define HBO   110720u   // 16 x 528 u16 bf16 h (stride 1056 B)
#define XSO   127616u   // 16 x 1040 fp8 xs = exp(z-m)*256
#define RMX   144256u   // 16x16 f32 row-max partials
#define RSM   145280u   // 16x16 f32 row-sum partials
#define LDS_TOTAL 146304

#define WAITVM_(N) asm volatile("s_waitcnt vmcnt(" #N ")" ::: "memory")
#define WAITVM(N) WAITVM_(N)

typedef const __attribute__((address_space(1))) void* gvp;
typedef __attribute__((address_space(3))) void* svp;

__global__ __launch_bounds__(1024, 4)
void lstm_fused(const float* __restrict__ x, const float* __restrict__ gum,
                const u8* __restrict__ w1f, const u16* __restrict__ wof,
                const u8* __restrict__ wef, const float* __restrict__ b1,
                const float* __restrict__ b_out, const float* __restrict__ b_emb,
                const float* __restrict__ sos, float* __restrict__ out)
{
    extern __shared__ char smem[];

    const u32 tid = threadIdx.x;
    const u32 w   = tid >> 6;        // wave 0..15
    const u32 l   = tid & 63u;
    const u32 q   = l >> 4;
    const u32 col = l & 15u;
    const int r0  = blockIdx.x << 4;

    const u32 wK  = w << 10;         // w*1024 : this wave's frag-pair offset (A/C)
    const u32 wK2 = w << 11;         // w*2048 : phase B frag-pair offset
    const u32 lB  = l << 4;          // l*16
    const u32 l8  = l << 3;          // l*8
    const u32 q8  = q << 3;
    const u32 colB776  = col * 776u;
    const u32 colB1040 = col * 1040u;
    const u32 colB1056 = col * 1056u;

    const char* w1p = (const char*)w1f;
    const char* wop = (const char*)wof;
    const char* wep = (const char*)wef;

#define ISS_A(C) do { u32 _c = (u32)(C); \
    u32 _o = (u32)__builtin_amdgcn_readfirstlane((int)(((_c & 3u) << 14) + wK)); \
    __builtin_amdgcn_global_load_lds((gvp)(w1p + ((size_t)_c << 14) + wK + lB), (svp)(smem + _o), 16, 0, 0); } while (0)
#define ISS_B(C) do { u32 _c = (u32)(C); \
    u32 _o = (u32)__builtin_amdgcn_readfirstlane((int)((_c % 3u) * 32768u + wK2)); \
    const char* _s = wop + ((size_t)_c << 15) + wK2 + lB; \
    __builtin_amdgcn_global_load_lds((gvp)_s,            (svp)(smem + _o),          16, 0, 0); \
    __builtin_amdgcn_global_load_lds((gvp)(_s + 1024),   (svp)(smem + _o + 1024u),  16, 0, 0); } while (0)
#define ISS_C(C) do { u32 _c = (u32)(C); \
    u32 _o = (u32)__builtin_amdgcn_readfirstlane((int)(((_c & 3u) << 14) + wK)); \
    __builtin_amdgcn_global_load_lds((gvp)(wep + ((size_t)_c << 14) + wK + lB), (svp)(smem + _o), 16, 0, 0); } while (0)

#define CONSA(G) { const char* _fb = smem + ((ca & 3u) << 14) + wK; \
    i64 _b0 = *(const i64*)(_fb + l8); i64 _b1 = *(const i64*)(_fb + 512u + l8); \
    acc[G][0] = __builtin_amdgcn_mfma_f32_16x16x32_fp8_fp8(a8, _b0, acc[G][0], 0, 0, 0); \
    acc[G][1] = __builtin_amdgcn_mfma_f32_16x16x32_fp8_fp8(a8, _b1, acc[G][1], 0, 0, 0); }
#define CONSB(HF) { const char* _fb = smem + (cb % 3u) * 32768u + wK2; \
    bf16x8 _f0 = *(const bf16x8*)(_fb + lB); bf16x8 _f1 = *(const bf16x8*)(_fb + 1024u + lB); \
    accB[HF][0] = __builtin_amdgcn_mfma_f32_16x16x32_bf16(af, _f0, accB[HF][0], 0, 0, 0); \
    accB[HF][1] = __builtin_amdgcn_mfma_f32_16x16x32_bf16(af, _f1, accB[HF][1], 0, 0, 0); }
#define CONSC(C2) { const char* _fb = smem + ((cc & 3u) << 14) + wK; \
    i64 _f0 = *(const i64*)(_fb + l8); i64 _f1 = *(const i64*)(_fb + 512u + l8); \
    i64 _a0 = *(const i64*)(smem + XSO + colB1040 + ((2u * (C2)) << 5) + q8); \
    i64 _a1 = *(const i64*)(smem + XSO + colB1040 + ((2u * (C2) + 1u) << 5) + q8); \
    accC = __builtin_amdgcn_mfma_f32_16x16x32_fp8_fp8(_a0, _f0, accC, 0, 0, 0); \
    accC = __builtin_amdgcn_mfma_f32_16x16x32_fp8_fp8(_a1, _f1, accC, 0, 0, 0); }

    // EOS row
    for (u32 i = tid; i < 16 * V_; i += 1024) {
        u32 b = i >> 10, v = i & (V_ - 1);
        out[((size_t)(r0 + b) * 33 + 32) * V_ + v] = (v == 0) ? 1.f : 0.f;
    }
    // e0 = sos*16 (fp8), h0 = x*16 (fp8)  [hB written every step before use]
    for (u32 i = tid; i < 16 * E_; i += 1024) {
        u32 b = i >> 8, k = i & (E_ - 1);
        *(u8*)(smem + AEO + b * 776u + k) = f2e4m3(sos[k] * 16.f);
    }
    for (u32 i = tid; i < 16 * H_; i += 1024) {
        u32 b = i >> 9, k = i & (H_ - 1);
        *(u8*)(smem + AEO + b * 776u + 256u + k) = f2e4m3(x[(r0 + b) * H_ + k] * 16.f);
    }

    // hoisted biases
    float bia[2], bfa[2], bga[2], boa[2];
    #pragma unroll
    for (int jj = 0; jj < 2; ++jj) {
        int j = (w << 5) + (jj << 4) + col;
        bia[jj] = b1[j];           bfa[jj] = b1[H_ + j];
        bga[jj] = b1[2 * H_ + j];  boa[jj] = b1[3 * H_ + j];
    }
    float bov[2][2];
    #pragma unroll
    for (int hf = 0; hf < 2; ++hf)
        #pragma unroll
        for (int jj = 0; jj < 2; ++jj)
            bov[hf][jj] = b_out[hf * 512 + (w << 5) + (jj << 4) + col];
    const float bem16 = b_emb[(w << 4) + col] * 16.f;

    float creg[2][4];
    #pragma unroll
    for (int jj = 0; jj < 2; ++jj)
        #pragma unroll
        for (int r = 0; r < 4; ++r) creg[jj][r] = 0.f;

    __syncthreads();

    const f32x4 fz = {0.f, 0.f, 0.f, 0.f};
    const float S1 = 1.f / 1024.f;            // 1/(A_SC*W_SC) = 1/(16*64)

    for (int t = 0; t < L_; ++t) {
        // =============== phase A: gates (fp8 x fp8) ===============
        f32x4 acc[4][2];
        #pragma unroll
        for (int g = 0; g < 4; ++g) { acc[g][0] = fz; acc[g][1] = fz; }

        ISS_A(0); ISS_A(1); ISS_A(2);
        u32 ca = 0;
        for (u32 ks = 0; ks < 23; ++ks) {
            i64 a8 = *(const i64*)(smem + AEO + colB776 + (ks << 5) + q8);
            #pragma unroll
            for (u32 g = 0; g < 4; ++g) {
                WAITVM(2);
                CONSA(g);
                ISS_A(ca + 3u);     // ca<=91 -> issues <=94
                ++ca;
            }
        }
        {   // ks = 23 peel (chunks 92..95)
            i64 a8 = *(const i64*)(smem + AEO + colB776 + (23u << 5) + q8);
            WAITVM(2); CONSA(0); ISS_A(95); ++ca;
            WAITVM(2); CONSA(1); ++ca;
            WAITVM(1); CONSA(2); ++ca;
            WAITVM(0); CONSA(3);
        }
        __syncthreads();            // all ae8 reads done before h overwrite

        #pragma unroll
        for (int jj = 0; jj < 2; ++jj) {
            int j = (w << 5) + (jj << 4) + col;
            #pragma unroll
            for (int r = 0; r < 4; ++r) {
                float gi = sig_(acc[0][jj][r] * S1 + bia[jj]);
                float gf = sig_(acc[1][jj][r] * S1 + bfa[jj]);
                float gg = tanh_(acc[2][jj][r] * S1 + bga[jj]);
                float go = sig_(acc[3][jj][r] * S1 + boa[jj]);
                float c  = gf * creg[jj][r] + gi * gg;
                creg[jj][r] = c;
                float h = go * tanh_(c);
                u32 b = (q << 2) + r;
                *(u8*)(smem + AEO + b * 776u + 256u + j) = f2e4m3(h * 16.f);
                *(u16*)(smem + HBO + b * 1056u + (u32)j * 2u) = f2bf(h);
            }
        }
        __syncthreads();            // h complete

        // =============== phase B: logits (bf16) + softmax ===============
        const float* gt = gum + (size_t)t * (B_ * V_) + (size_t)r0 * V_;
        float gr[2][2][4];
        #pragma unroll
        for (int hf = 0; hf < 2; ++hf)
            #pragma unroll
            for (int jj = 0; jj < 2; ++jj) {
                int v = hf * 512 + (w << 5) + (jj << 4) + col;
                #pragma unroll
                for (int r = 0; r < 4; ++r)
                    gr[hf][jj][r] = gt[((q << 2) + r) * V_ + v];
            }

        f32x4 accB[2][2];
        accB[0][0] = fz; accB[0][1] = fz; accB[1][0] = fz; accB[1][1] = fz;
        ISS_B(0); ISS_B(1);
        u32 cb = 0;
        for (u32 ks = 0; ks < 16; ++ks) {       // half 0, cb 0..15
            bf16x8 af = *(const bf16x8*)(smem + HBO + colB1056 + (ks << 6) + (q << 4));
            WAITVM(2);
            CONSB(0);
            ISS_B(cb + 2u);
            ++cb;
        }
        for (u32 ks = 0; ks < 14; ++ks) {       // half 1, cb 16..29
            bf16x8 af = *(const bf16x8*)(smem + HBO + colB1056 + (ks << 6) + (q << 4));
            WAITVM(2);
            CONSB(1);
            ISS_B(cb + 2u);                     // cb<=29 -> issues <=31
            ++cb;
        }
        {   // peel cb=30 (half1 ks14), cb=31 (half1 ks15)
            bf16x8 af = *(const bf16x8*)(smem + HBO + colB1056 + (14u << 6) + (q << 4));
            WAITVM(2); CONSB(1); ++cb;
            af = *(const bf16x8*)(smem + HBO + colB1056 + (15u << 6) + (q << 4));
            WAITVM(0); CONSB(1);
        }

        // z, row-max, exp, row-sum
        float z[2][2][4];
        float mx[4];
        #pragma unroll
        for (int r = 0; r < 4; ++r) mx[r] = -1e30f;
        #pragma unroll
        for (int hf = 0; hf < 2; ++hf)
            #pragma unroll
            for (int jj = 0; jj < 2; ++jj)
                #pragma unroll
                for (int r = 0; r < 4; ++r) {
                    float zz = accB[hf][jj][r] + bov[hf][jj] + gr[hf][jj][r];
                    z[hf][jj][r] = zz;
                    mx[r] = fmaxf(mx[r], zz);
                }
        #pragma unroll
        for (int m = 1; m < 16; m <<= 1)
            #pragma unroll
            for (int r = 0; r < 4; ++r) mx[r] = fmaxf(mx[r], __shfl_xor(mx[r], m, 64));
        if (col == 0) {
            #pragma unroll
            for (int r = 0; r < 4; ++r)
                *(float*)(smem + RMX + (((q << 2) + r) * 16u + w) * 4u) = mx[r];
        }
        __syncthreads();
        float m_[4];
        #pragma unroll
        for (int r = 0; r < 4; ++r) {
            float mm = -1e30f;
            #pragma unroll
            for (int ww = 0; ww < 16; ++ww)
                mm = fmaxf(mm, *(const float*)(smem + RMX + (((q << 2) + r) * 16u + ww) * 4u));
            m_[r] = mm;
        }
        float eb[2][2][4];
        float ps[4] = {0.f, 0.f, 0.f, 0.f};
        #pragma unroll
        for (int hf = 0; hf < 2; ++hf)
            #pragma unroll
            for (int jj = 0; jj < 2; ++jj)
                #pragma unroll
                for (int r = 0; r < 4; ++r) {
                    float Ee = __expf(z[hf][jj][r] - m_[r]);
                    eb[hf][jj][r] = Ee;
                    ps[r] += Ee;
                }
        #pragma unroll
        for (int m = 1; m < 16; m <<= 1)
            #pragma unroll
            for (int r = 0; r < 4; ++r) ps[r] += __shfl_xor(ps[r], m, 64);
        if (col == 0) {
            #pragma unroll
            for (int r = 0; r < 4; ++r)
                *(float*)(smem + RSM + (((q << 2) + r) * 16u + w) * 4u) = ps[r];
        }
        // stage xs = exp(z-m)*256 as fp8 (usable before sum known)
        #pragma unroll
        for (int hf = 0; hf < 2; ++hf)
            #pragma unroll
            for (int jj = 0; jj < 2; ++jj) {
                u32 v = (u32)(hf * 512 + (w << 5) + (jj << 4) + col);
                #pragma unroll
                for (int r = 0; r < 4; ++r)
                    *(u8*)(smem + XSO + ((q << 2) + r) * 1040u + v) = f2e4m3(eb[hf][jj][r] * 256.f);
            }
        __syncthreads();
        float invs[4];
        #pragma unroll
        for (int r = 0; r < 4; ++r) {
            float s = 0.f;
            #pragma unroll
            for (int ww = 0; ww < 16; ++ww)
                s += *(const float*)(smem + RSM + (((q << 2) + r) * 16u + ww) * 4u);
            invs[r] = 1.f / s;
        }
        // normalized softmax out (fp32)
        #pragma unroll
        for (int hf = 0; hf < 2; ++hf)
            #pragma unroll
            for (int jj = 0; jj < 2; ++jj) {
                int v = hf * 512 + (w << 5) + (jj << 4) + col;
                #pragma unroll
                for (int r = 0; r < 4; ++r) {
                    int b = (q << 2) + r;
                    out[((size_t)(r0 + b) * 33 + t) * V_ + v] = eb[hf][jj][r] * invs[r];
                }
            }

        // =============== phase C: e_new (fp8 x fp8) ===============
        f32x4 accC = fz;
        ISS_C(0); ISS_C(1); ISS_C(2);
        u32 cc = 0;
        for (u32 c2 = 0; c2 < 12; ++c2) {
            WAITVM(2);
            CONSC(c2);
            ISS_C(cc + 3u);                    // cc<=11 -> issues <=14
            ++cc;
        }
        WAITVM(2); CONSC(12u); ISS_C(15); ++cc;
        WAITVM(2); CONSC(13u); ++cc;
        WAITVM(1); CONSC(14u); ++cc;
        WAITVM(0); CONSC(15u);

        {   // e = accC*invs/(256*64) + b_emb ; store e*16 as fp8
            u32 ce = (w << 4) + col;
            #pragma unroll
            for (int r = 0; r < 4; ++r) {
                float e_ = accC[r] * invs[r] * (16.f / 16384.f) + bem16;
                *(u8*)(smem + AEO + ((q << 2) + r) * 776u + ce) = f2e4m3(e_);
            }
        }
        __syncthreads();            // e complete before next step's phase A
    }
#undef ISS_A
#undef ISS_B
#undef ISS_C
#undef CONSA
#undef CONSB
#undef CONSC
}

extern "C" void kernel_launch(void* const* d_in, const int* in_sizes, int n_in,
                              void* d_out, int out_size, void* d_ws, size_t ws_size,
                              hipStream_t stream) {
    const float* x     = (const float*)d_in[0];
    const float* gum   = (const float*)d_in[1];
    const float* W_ih  = (const float*)d_in[2];
    const float* W_hh  = (const float*)d_in[3];
    const float* b_ih  = (const float*)d_in[4];
    const float* b_hh  = (const float*)d_in[5];
    const float* W_out = (const float*)d_in[6];
    const float* b_out = (const float*)d_in[7];
    const float* W_emb = (const float*)d_in[8];
    const float* b_emb = (const float*)d_in[9];
    const float* sos   = (const float*)d_in[10];
    float* out = (float*)d_out;

    char* ws = (char*)d_ws;
    u8*    w1f = (u8*)(ws);                    // 1,572,864 B (fp8)
    u16*   wof = (u16*)(ws + 1572864);         // 1,048,576 B (bf16)
    u8*    wef = (u8*)(ws + 2621440);          //   262,144 B (fp8)
    float* b1  = (float*)(ws + 2883584);       //     8,192 B

    hipFuncSetAttribute((const void*)lstm_fused,
                        hipFuncAttributeMaxDynamicSharedMemorySize, LDS_TOTAL);

    prep<<<9224, 256, 0, stream>>>(W_ih, W_hh, b_ih, b_hh, W_out, W_emb,
                                   w1f, wof, wef, b1);
    lstm_fused<<<128, 1024, LDS_TOTAL, stream>>>(x, gum, w1f, wof, wef, b1,
                                                 b_out, b_emb, sos, out);
}